// Round 9
// baseline (1410.376 us; speedup 1.0000x reference)
//
#include <hip/hip_runtime.h>
#include <hip/hip_bf16.h>
#include <hip/hip_fp16.h>
#include <math.h>

#define B_ 4
#define N_ 2048
#define D_ 512

typedef __bf16    bf16x8  __attribute__((ext_vector_type(8)));
typedef float     floatx4 __attribute__((ext_vector_type(4)));
typedef _Float16  half8   __attribute__((ext_vector_type(8)));

#if __has_builtin(__builtin_amdgcn_exp2f)
__device__ __forceinline__ float fexp2(float x) { return __builtin_amdgcn_exp2f(x); }
#else
__device__ __forceinline__ float fexp2(float x) { return exp2f(x); }
#endif
#if __has_builtin(__builtin_amdgcn_logf)
__device__ __forceinline__ float flog2(float x) { return __builtin_amdgcn_logf(x); }
#else
__device__ __forceinline__ float flog2(float x) { return __log2f(x); }
#endif

// ---------------------------------------------------------------------------
__device__ __forceinline__ void gload16(const void* g, void* l) {
  __builtin_amdgcn_global_load_lds(
      (const __attribute__((address_space(1))) void*)g,
      (__attribute__((address_space(3))) void*)l, 16, 0, 0);
}

// ---------------------------------------------------------------------------
// L2-normalize rows of (rows, 512) f32 -> bf16
// ---------------------------------------------------------------------------
__global__ __launch_bounds__(256) void norm_kernel(const float* __restrict__ in,
                                                   __hip_bfloat16* __restrict__ out) {
  const size_t row = blockIdx.x;
  const int t = threadIdx.x;
  const float* src = in + row * D_;
  float v0 = src[t], v1 = src[t + 256];
  float ss = fmaf(v0, v0, v1 * v1);
#pragma unroll
  for (int off = 1; off < 64; off <<= 1) ss += __shfl_xor(ss, off);
  __shared__ float red[4];
  if ((t & 63) == 0) red[t >> 6] = ss;
  __syncthreads();
  const float tot = red[0] + red[1] + red[2] + red[3];
  const float scale = 1.0f / fmaxf(sqrtf(tot), 1e-12f);
  out[row * D_ + t]       = __float2bfloat16(v0 * scale);
  out[row * D_ + t + 256] = __float2bfloat16(v1 * scale);
}

// ---------------------------------------------------------------------------
// Batched NT GEMM producing the 3 Gram matrices in one dispatch.
// ---------------------------------------------------------------------------
__global__ __launch_bounds__(256) void gram_gemm(const __hip_bfloat16* __restrict__ X,
                                                 const __hip_bfloat16* __restrict__ Y,
                                                 __half* __restrict__ Gxy,
                                                 __half* __restrict__ Gxx,
                                                 __half* __restrict__ Gyy) {
  __shared__ __hip_bfloat16 As[128 * 32];
  __shared__ __hip_bfloat16 Bs[128 * 32];
  const int t = threadIdx.x;
  const int wave = t >> 6, lane = t & 63;
  const int bm0 = blockIdx.x * 128, bn0 = blockIdx.y * 128;
  const int mat = blockIdx.z >> 2;
  const size_t bb = blockIdx.z & 3;
  const __hip_bfloat16* Ab = (mat == 2 ? Y : X) + bb * (size_t)(N_ * D_);
  const __hip_bfloat16* Bb = (mat == 1 ? X : Y) + bb * (size_t)(N_ * D_);
  __half* Gb = (mat == 0 ? Gxy : mat == 1 ? Gxx : Gyy) + bb * (size_t)N_ * N_;

  floatx4 acc[4][4] = {};
  const int wr = wave >> 1, wc = wave & 1;
  const int srow = t >> 2;
  const int scol = (t & 3) * 8;
  char* AsB = (char*)As;
  char* BsB = (char*)Bs;
  const int ldsOff = wave * 1024;

  for (int k0 = 0; k0 < D_; k0 += 32) {
    __syncthreads();
    gload16(Ab + (size_t)(bm0 + srow)      * D_ + k0 + scol, AsB + ldsOff);
    gload16(Ab + (size_t)(bm0 + 64 + srow) * D_ + k0 + scol, AsB + 4096 + ldsOff);
    gload16(Bb + (size_t)(bn0 + srow)      * D_ + k0 + scol, BsB + ldsOff);
    gload16(Bb + (size_t)(bn0 + 64 + srow) * D_ + k0 + scol, BsB + 4096 + ldsOff);
    __syncthreads();

    const int lrow = lane & 15, lk = (lane >> 4) * 8;
    bf16x8 af[4], bfr[4];
#pragma unroll
    for (int mi = 0; mi < 4; ++mi)
      af[mi] = *(const bf16x8*)((const char*)As + ((wr * 64 + mi * 16 + lrow) * 32 + lk) * 2);
#pragma unroll
    for (int ni = 0; ni < 4; ++ni)
      bfr[ni] = *(const bf16x8*)((const char*)Bs + ((wc * 64 + ni * 16 + lrow) * 32 + lk) * 2);
#pragma unroll
    for (int mi = 0; mi < 4; ++mi)
#pragma unroll
      for (int ni = 0; ni < 4; ++ni)
        acc[mi][ni] = __builtin_amdgcn_mfma_f32_16x16x32_bf16(af[mi], bfr[ni], acc[mi][ni], 0, 0, 0);
  }

  const int orow = (lane >> 4) * 4, ocol = lane & 15;
#pragma unroll
  for (int mi = 0; mi < 4; ++mi)
#pragma unroll
    for (int ni = 0; ni < 4; ++ni) {
      const int row = bm0 + wr * 64 + mi * 16 + orow;
      const int col = bn0 + wc * 64 + ni * 16 + ocol;
#pragma unroll
      for (int r = 0; r < 4; ++r)
        Gb[(size_t)(row + r) * N_ + col] = __float2half(acc[mi][ni][r]);
    }
}

// ---------------------------------------------------------------------------
// Fused streaming pass, full-row waves (R1's proven 5.7 TB/s layout) +
// predicted-shift algebra (R8, no max chains, 1 exp2/elem) + plain sums.
// 768 blocks = 3/CU, mat = bid % 3:
//   mat 0 (Gxy): row sums -> f_ba (slot 0); plain col sums -> colPart
//   mat 1 (Gxx): row sums -> f_aa (slot 2)
//   mat 2 (Gyy): row sums -> g_bb (slot 3)
// Block = (mat, b, 32-row stripe); wave owns 8 FULL rows (4 sequential 1KB
// chunks per row). w = 2^(ieL*G + hh[c] + hrD[row]) is the plan entry; it
// feeds rsum (tree add) and colsum[32] (plain add). No cross-lane ops and no
// fmax in the loop; add-only butterflies batched at the end. colsum merges
// across waves via 32KB LDS (plain adds) -> colPart holds plain sums.
// Finalize: v_row = -eps*ln2*(log2(rsum) - hrD). Col unshift happens in merge.
// MODE 0: init write. MODE 1: damped 0.5(old+new). MODE 2: loss accumulate.
// ---------------------------------------------------------------------------
#define L2E_ 1.44269504088896f
#define LN2_ 0.69314718055995f

template <int MODE>
__global__ __launch_bounds__(256) void sink_stream(
    const __half* __restrict__ Gxy, const __half* __restrict__ Gxx,
    const __half* __restrict__ Gyy,
    const float* __restrict__ potOld, float* __restrict__ potNew,
    float* __restrict__ colPart, float eps, float* __restrict__ out) {
  __shared__ float cw[4][2048];   // 32 KB cross-wave column merge (mat 0)
  __shared__ float redls[4];

  const int bid = blockIdx.x;
  const int mat = bid % 3;
  const int rem = bid / 3;                 // 0..255
  const int b = rem >> 6, stripe = rem & 63;
  const int lane = threadIdx.x & 63, wave = threadIdx.x >> 6;

  const float inv_eps = 1.0f / eps;
  const float ieL  = inv_eps * L2E_;
  const float hbL  = (-7.62461898616f - inv_eps) * L2E_;  // (-log 2048 - 1/eps)*log2e
  const float negEpsLn2 = -eps * LN2_;

  const __half* G = (mat == 0 ? Gxy : mat == 1 ? Gxx : Gyy) + (size_t)b * N_ * N_;
  const int hIdx = (mat == 0) ? 1 : (mat == 1) ? 2 : 3;
  const int oIdx = (mat == 0) ? 0 : hIdx;
  const float* potH = potOld + ((size_t)hIdx * B_ + b) * N_;
  const float* potO = potOld + ((size_t)oIdx * B_ + b) * N_;
  float*       potW = potNew + ((size_t)oIdx * B_ + b) * N_;

  const int rbase = stripe * 32 + wave * 8;   // this wave's 8 rows

  // transformed column potentials for the lane's 32 columns (4 chunks x 8)
  float hh[32];
  if constexpr (MODE == 0) {
#pragma unroll
    for (int c = 0; c < 32; ++c) hh[c] = hbL;
  } else {
#pragma unroll
    for (int p = 0; p < 4; ++p) {
      const float4 a = *(const float4*)(potH + p * 512 + lane * 8);
      const float4 c4 = *(const float4*)(potH + p * 512 + lane * 8 + 4);
      hh[p * 8 + 0] = fmaf(a.x, ieL, hbL);  hh[p * 8 + 1] = fmaf(a.y, ieL, hbL);
      hh[p * 8 + 2] = fmaf(a.z, ieL, hbL);  hh[p * 8 + 3] = fmaf(a.w, ieL, hbL);
      hh[p * 8 + 4] = fmaf(c4.x, ieL, hbL); hh[p * 8 + 5] = fmaf(c4.y, ieL, hbL);
      hh[p * 8 + 6] = fmaf(c4.z, ieL, hbL); hh[p * 8 + 7] = fmaf(c4.w, ieL, hbL);
    }
  }

  // row-side shifts (pure numerical shift, removed exactly at finalize)
  float hrD[8];
  if constexpr (MODE == 0) {
#pragma unroll
    for (int r = 0; r < 8; ++r) hrD[r] = 0.0f;
  } else {
#pragma unroll
    for (int r = 0; r < 8; ++r) hrD[r] = potO[rbase + r] * ieL;
  }

  float colsum[32];
#pragma unroll
  for (int c = 0; c < 32; ++c) colsum[c] = 0.0f;
  float rsum[8];

  const __half* grow = G + (size_t)rbase * N_ + lane * 8;

#pragma unroll
  for (int it = 0; it < 4; ++it) {
    half8 r0c[4], r1c[4];
#pragma unroll
    for (int p = 0; p < 4; ++p) {
      r0c[p] = *(const half8*)(grow + (size_t)(it * 2)     * N_ + p * 512);
      r1c[p] = *(const half8*)(grow + (size_t)(it * 2 + 1) * N_ + p * 512);
    }
    const float h0 = hrD[it * 2], h1 = hrD[it * 2 + 1];
    float a0 = 0.0f, a1 = 0.0f;
#pragma unroll
    for (int p = 0; p < 4; ++p) {
      float s0 = 0.0f, s1 = 0.0f;
#pragma unroll
      for (int e = 0; e < 8; ++e) {
        const int c = p * 8 + e;
        const float w0 = fexp2(fmaf((float)r0c[p][e], ieL, hh[c] + h0));
        const float w1 = fexp2(fmaf((float)r1c[p][e], ieL, hh[c] + h1));
        s0 += w0;
        s1 += w1;
        if (mat == 0) colsum[c] += w0 + w1;
      }
      a0 += s0;
      a1 += s1;
    }
    rsum[it * 2] = a0;
    rsum[it * 2 + 1] = a1;
  }

  // add-only butterflies, 8 independent chains
#pragma unroll
  for (int r = 0; r < 8; ++r) {
    float s = rsum[r];
#pragma unroll
    for (int off = 1; off < 64; off <<= 1) s += __shfl_xor(s, off);
    rsum[r] = s;
  }

  // row finalize: lane 0 of each wave writes its 8 rows
  float lsum = 0.0f;
  if (lane == 0) {
#pragma unroll
    for (int r = 0; r < 8; ++r) {
      const float v = negEpsLn2 * (flog2(rsum[r]) - hrD[r]);
      if constexpr (MODE == 0) {
        potW[rbase + r] = v;
      } else if constexpr (MODE == 1) {
        const float vOld = -negEpsLn2 * hrD[r];   // recover old potential
        potW[rbase + r] = 0.5f * (vOld + v);
      } else {
        lsum += v;
      }
    }
  }

  // cross-wave column merge (mat 0): plain adds via LDS
  if (mat == 0) {
#pragma unroll
    for (int p = 0; p < 4; ++p) {
      *(float4*)&cw[wave][p * 512 + lane * 8] =
          make_float4(colsum[p * 8 + 0], colsum[p * 8 + 1],
                      colsum[p * 8 + 2], colsum[p * 8 + 3]);
      *(float4*)&cw[wave][p * 512 + lane * 8 + 4] =
          make_float4(colsum[p * 8 + 4], colsum[p * 8 + 5],
                      colsum[p * 8 + 6], colsum[p * 8 + 7]);
    }
  }
  __syncthreads();
  if (mat == 0) {
    const int cbase = threadIdx.x * 8;   // 256 threads x 8 cols
    float o[8];
#pragma unroll
    for (int k = 0; k < 8; ++k)
      o[k] = ((cw[0][cbase + k] + cw[1][cbase + k]) +
              (cw[2][cbase + k] + cw[3][cbase + k]));
    float* cp = colPart + ((size_t)(b * 64 + stripe) * 2048 + cbase);
    *(float4*)cp       = make_float4(o[0], o[1], o[2], o[3]);
    *(float4*)(cp + 4) = make_float4(o[4], o[5], o[6], o[7]);
  }

  if constexpr (MODE == 2) {
    if (lane == 0) redls[wave] = lsum;
    __syncthreads();
    if (threadIdx.x == 0) {
      const float sign = (mat == 0) ? 1.0f : -1.0f;
      atomicAdd(out, sign * (redls[0] + redls[1] + redls[2] + redls[3]) *
                         (1.0f / (2048.0f * B_)));
    }
  }
}

// ---------------------------------------------------------------------------
// Merge plain column sums across 64 stripes -> g_ab (slot 1).
// 128 blocks x 256. Block = 64 global columns (lane); wave `sub` adds stripes
// [sub*16, sub*16+16); LDS add-merge; sub 0 finalizes with the g-unshift.
// ---------------------------------------------------------------------------
template <int MODE>
__global__ __launch_bounds__(256) void sink_merge(
    const float* __restrict__ colPart, const float* __restrict__ potOld,
    float* __restrict__ potNew, float eps, float* __restrict__ out) {
  __shared__ float mp[3][64];
  const int lane = threadIdx.x & 63, sub = threadIdx.x >> 6;
  const int colg = blockIdx.x * 64 + lane;          // 0..8191
  const int b = colg >> 11, col = colg & 2047;
  const float ieL = (1.0f / eps) * L2E_;
  const float negEpsLn2 = -eps * LN2_;

  float s = 0.0f;
  const float* cp = colPart + ((size_t)(b * 64 + sub * 16)) * 2048 + col;
#pragma unroll
  for (int st = 0; st < 16; ++st) s += cp[(size_t)st * 2048];
  if (sub != 0) mp[sub - 1][lane] = s;
  __syncthreads();

  float vfin = 0.0f;
  if (sub == 0) {
    s += (mp[0][lane] + mp[1][lane]) + mp[2][lane];
    const float gsh = (MODE == 0) ? 0.0f
                    : potOld[((size_t)1 * B_ + b) * N_ + col] * ieL;
    const float v = negEpsLn2 * (flog2(s) - gsh);
    if constexpr (MODE == 0) {
      potNew[((size_t)1 * B_ + b) * N_ + col] = v;
    } else if constexpr (MODE == 1) {
      const float vOld = -negEpsLn2 * gsh;          // recover old potential
      potNew[((size_t)1 * B_ + b) * N_ + col] = 0.5f * (vOld + v);
    } else {
      vfin = v;
    }
  }

  if constexpr (MODE == 2) {
#pragma unroll
    for (int off = 1; off < 64; off <<= 1) vfin += __shfl_xor(vfin, off);
    __shared__ float red[4];
    if ((threadIdx.x & 63) == 0) red[sub] = vfin;
    __syncthreads();
    if (threadIdx.x == 0)
      atomicAdd(out, (red[0] + red[1] + red[2] + red[3]) * (1.0f / (2048.0f * B_)));
  }
}

// ---------------------------------------------------------------------------
extern "C" void kernel_launch(void* const* d_in, const int* in_sizes, int n_in,
                              void* d_out, int out_size, void* d_ws, size_t ws_size,
                              hipStream_t stream) {
  const float* E_p = (const float*)d_in[0];
  const float* E_t = (const float*)d_in[1];
  float* out = (float*)d_out;
  char* ws = (char*)d_ws;

  size_t off = 0;
  auto alloc = [&](size_t bytes) {
    void* p = ws + off;
    off += (bytes + 255) & ~(size_t)255;
    return p;
  };
  __hip_bfloat16* Xb = (__hip_bfloat16*)alloc((size_t)B_ * N_ * D_ * 2);
  __hip_bfloat16* Yb = (__hip_bfloat16*)alloc((size_t)B_ * N_ * D_ * 2);
  __half* Gxy = (__half*)alloc((size_t)B_ * N_ * N_ * 2);
  __half* Gxx = (__half*)alloc((size_t)B_ * N_ * N_ * 2);
  __half* Gyy = (__half*)alloc((size_t)B_ * N_ * N_ * 2);
  float* potA = (float*)alloc((size_t)4 * B_ * N_ * 4);
  float* potB = (float*)alloc((size_t)4 * B_ * N_ * 4);
  float* colPart = (float*)alloc((size_t)B_ * 64 * 2048 * 4);

  norm_kernel<<<B_ * N_, 256, 0, stream>>>(E_p, Xb);
  norm_kernel<<<B_ * N_, 256, 0, stream>>>(E_t, Yb);

  dim3 gg(16, 16, 12);
  gram_gemm<<<gg, 256, 0, stream>>>(Xb, Yb, Gxy, Gxx, Gyy);

  // epsilon schedule (numpy arange semantics, double precision)
  float epsl[48];
  int ne = 0;
  epsl[ne++] = 4.0f;
  {
    const double lstart = 2.0 * log(2.0);
    const double lstop  = 2.0 * log(0.05);
    const double lstep  = 2.0 * log(0.9);
    for (int k = 0;; ++k) {
      const double v = lstart + k * lstep;
      if (!(v > lstop)) break;
      epsl[ne++] = (float)exp(v);
    }
  }
  epsl[ne++] = 0.0025f;

  (void)hipMemsetAsync(d_out, 0, sizeof(float), stream);

  // init at eps0
  sink_stream<0><<<768, 256, 0, stream>>>(Gxy, Gxx, Gyy, potA, potA, colPart,
                                          epsl[0], nullptr);
  sink_merge<0><<<128, 256, 0, stream>>>(colPart, potA, potA, epsl[0], nullptr);

  // damped scan over the schedule
  float* cur = potA;
  float* nxt = potB;
  for (int i = 0; i < ne; ++i) {
    sink_stream<1><<<768, 256, 0, stream>>>(Gxy, Gxx, Gyy, cur, nxt, colPart,
                                            epsl[i], nullptr);
    sink_merge<1><<<128, 256, 0, stream>>>(colPart, cur, nxt, epsl[i], nullptr);
    float* tmp = cur; cur = nxt; nxt = tmp;
  }

  // final extrapolation + loss
  sink_stream<2><<<768, 256, 0, stream>>>(Gxy, Gxx, Gyy, cur, cur, colPart,
                                          epsl[ne - 1], out);
  sink_merge<2><<<128, 256, 0, stream>>>(colPart, cur, cur, epsl[ne - 1], out);
}